// Round 4
// baseline (109.692 us; speedup 1.0000x reference)
//
#include <hip/hip_runtime.h>

// RWKV-4 WKV forward. B=16, T=1024, C=2048, fp32.
// One thread per (b,c). k/v staged via global_load_lds (16B/lane) into a
// 6-buffer LDS ring, 5 tiles (80 timesteps) prefetched ahead, counted
// s_waitcnt vmcnt(N) gates. y staged in LDS and stored as 4x dwordx4 per
// tile so stores contribute exactly 4 vmcnt items per tile -> steady-state
// newer-ops at the wait is exactly 40 loads + 16 stores = 56.

#define T_DIM 1024
#define TILE 16                  // timesteps per tile
#define NTILES (T_DIM / TILE)    // 64
#define NBUF 6                   // LDS ring depth (5 tiles prefetch ahead)
#define BUF_DW 2048              // 16 t * (64 k + 64 v) dwords = 8 KB

typedef const __attribute__((address_space(1))) float* gptr_t;
typedef __attribute__((address_space(3))) float* lptr_t;

__global__ __launch_bounds__(64, 1) void wkv_fwd_kernel(
    const float* __restrict__ w, const float* __restrict__ u,
    const float* __restrict__ kk, const float* __restrict__ vv,
    float* __restrict__ y, int T, int C)
{
    __shared__ __align__(16) float lds[NBUF * BUF_DW + TILE * 64];  // 48KB + 4KB y

    const int lane = threadIdx.x;
    const int c0 = blockIdx.x * 64;
    const int b  = blockIdx.y;
    const int c  = c0 + lane;

    const float wc = w[c];
    const float uc = u[c];

    const size_t cbase = (size_t)b * T * C + c0;
    // per-lane source for 16B global_load_lds: t-row (lane>>4), 4 c's at (lane&15)*4.
    const size_t lane_off = (size_t)(lane >> 4) * C + (size_t)(lane & 15) * 4;
    const float* kpf = kk + cbase + lane_off;
    const float* vpf = vv + cbase + lane_off;
    float* ybase = y + cbase;            // + t*C + c

    float* ylds = &lds[NBUF * BUF_DW];   // [16 t][64 c]

    // issue one 16-t tile into buffer bi: 4 K-instrs + 4 V-instrs (8 vmcnt items)
    auto issue_tile = [&](int bi) {
        float* dst = &lds[bi * BUF_DW];
#pragma unroll
        for (int g = 0; g < 4; ++g) {
            __builtin_amdgcn_global_load_lds((gptr_t)kpf, (lptr_t)(dst + g * 512),       16, 0, 0);
            __builtin_amdgcn_global_load_lds((gptr_t)vpf, (lptr_t)(dst + g * 512 + 256), 16, 0, 0);
            kpf += 4 * C;
            vpf += 4 * C;
        }
    };

    float p = 0.f, q = 0.f, o = -1e38f;

    // prologue: tiles 0..4 in flight (40 loads)
#pragma unroll 1
    for (int n = 0; n < NBUF - 1; ++n) issue_tile(n);

#pragma unroll 1
    for (int i = 0; i < NTILES; ++i) {
        if (i + NBUF - 1 < NTILES) issue_tile((i + NBUF - 1) % NBUF);

        // Exact FIFO count of vmcnt items issued AFTER tile i's 8 loads:
        //   loads:  8 * min(5, 63 - i)
        //   stores: 4 * min(4, i)
        // Waiting to that count == "tile i's loads have landed", nothing more.
        {
            const int nc = 8 * (63 - i < 5 ? 63 - i : 5) + 4 * (i < 4 ? i : 4);
            switch (nc) {
                case  0: asm volatile("s_waitcnt vmcnt(0)"  ::: "memory"); break;
                case  8: asm volatile("s_waitcnt vmcnt(8)"  ::: "memory"); break;
                case 16: asm volatile("s_waitcnt vmcnt(16)" ::: "memory"); break;
                case 24: asm volatile("s_waitcnt vmcnt(24)" ::: "memory"); break;
                case 32: asm volatile("s_waitcnt vmcnt(32)" ::: "memory"); break;
                case 40: asm volatile("s_waitcnt vmcnt(40)" ::: "memory"); break;
                case 44: asm volatile("s_waitcnt vmcnt(44)" ::: "memory"); break;
                case 48: asm volatile("s_waitcnt vmcnt(48)" ::: "memory"); break;
                case 52: asm volatile("s_waitcnt vmcnt(52)" ::: "memory"); break;
                default: asm volatile("s_waitcnt vmcnt(56)" ::: "memory"); break;
            }
        }
        __builtin_amdgcn_sched_barrier(0);

        const float* buf = &lds[(i % NBUF) * BUF_DW];
#pragma unroll
        for (int j = 0; j < TILE; ++j) {
            const float kt = buf[(j >> 2) * 512 + (j & 3) * 64 + lane];
            const float vt = buf[(j >> 2) * 512 + 256 + (j & 3) * 64 + lane];

            // output at t: one of A/E is exactly 1 -> single exp
            const float uk = uc + kt;
            const float dd = o - uk;            // >=0 -> A=1,E=e ; <0 -> A=e,E=1
            const float e1 = __expf(-fabsf(dd));
            const float A  = dd >= 0.f ? 1.f : e1;
            const float E  = dd >= 0.f ? e1 : 1.f;
            ylds[j * 64 + lane] = __fdividef(fmaf(A, p, E * vt), fmaf(A, q, E));

            // state update
            const float wo = wc + o;
            const float d2 = wo - kt;
            const float e2 = __expf(-fabsf(d2));
            const float A2 = d2 >= 0.f ? 1.f : e2;
            const float E2 = d2 >= 0.f ? e2 : 1.f;
            p = fmaf(A2, p, E2 * vt);
            q = fmaf(A2, q, E2);
            o = fmaxf(wo, kt);
        }

        // y tile out: 4 coalesced dwordx4 stores (4 vmcnt items/tile)
#pragma unroll
        for (int g = 0; g < 4; ++g) {
            const int   r  = g * 4 + (lane >> 4);
            const float4 yv = *reinterpret_cast<const float4*>(
                &ylds[r * 64 + (lane & 15) * 4]);
            *reinterpret_cast<float4*>(
                &ybase[(size_t)(i * TILE + r) * C + (lane & 15) * 4]) = yv;
        }
    }
}

extern "C" void kernel_launch(void* const* d_in, const int* in_sizes, int n_in,
                              void* d_out, int out_size, void* d_ws, size_t ws_size,
                              hipStream_t stream) {
    // inputs: 0=B, 1=T, 2=C (scalars), 3=w[C], 4=u[C], 5=k[B*T*C], 6=v[B*T*C]
    const float* w = (const float*)d_in[3];
    const float* u = (const float*)d_in[4];
    const float* k = (const float*)d_in[5];
    const float* v = (const float*)d_in[6];
    float* y = (float*)d_out;

    const int C = in_sizes[3];            // 2048
    const int T = T_DIM;                  // 1024 (fixed by problem)
    const int B = in_sizes[5] / (T * C);  // 16

    dim3 grid(C / 64, B);
    dim3 block(64);
    wkv_fwd_kernel<<<grid, block, 0, stream>>>(w, u, k, v, y, T, C);
}